// Round 2
// baseline (208.160 us; speedup 1.0000x reference)
//
#include <hip/hip_runtime.h>
#include <hip/hip_fp16.h>

// AttentionBase: B=32 (2 batch x 16 heads), N=2048, D=64, fp32 in/out.
// Flash-attention fwd, fp16 MFMA (16x16x16) with fp32 accum.
// Swapped QK^T trick: compute S^T = K @ Q^T so each lane owns one q-row's
// scores (col=lane&15=q), making softmax lane-local + 2 shfls, and P^T regs
// land exactly in the PV MFMA B-fragment layout (k=(lane>>4)*4+j == reg j).

using f16 = _Float16;
typedef __attribute__((ext_vector_type(4))) f16   f16x4;
typedef __attribute__((ext_vector_type(4))) float f32x4;

constexpr int   N    = 2048;
constexpr int   D    = 64;
constexpr float SL2E = 0.125f * 1.4426950408889634f;  // SCALE * log2(e), folded into Q

__global__ __launch_bounds__(256, 2) void fattn(const float* __restrict__ Qg,
                                                const float* __restrict__ Kg,
                                                const float* __restrict__ Vg,
                                                float* __restrict__ Og)
{
    // LDS: K tile [64][68] f16 (pad +4 to break bank conflicts) and V^T tile
    // [64][68] f16. Epilogue reuses the whole 17408B as 4x float[16][68].
    __shared__ alignas(16) char smem[2 * 64 * 68 * sizeof(f16)];
    f16 (*Kl)[68] = reinterpret_cast<f16(*)[68]>(smem);
    f16 (*Vt)[68] = reinterpret_cast<f16(*)[68]>(smem + 64 * 68 * sizeof(f16));

    const int tid  = threadIdx.x;
    const int wave = tid >> 6;
    const int lane = tid & 63;
    const int g    = lane >> 4;   // 4-lane-group index (0..3)
    const int qi   = lane & 15;   // q index within wave tile / A-row index

    const int bh = blockIdx.x >> 5;  // batch-head 0..31
    const int qt = blockIdx.x & 31;  // q tile 0..31 (64 rows each)

    const size_t base = (size_t)bh * N * D;
    const float4* K4 = reinterpret_cast<const float4*>(Kg + base);
    const float4* V4 = reinterpret_cast<const float4*>(Vg + base);

    // Q fragments (B-operand of S^T mfma): lane holds Q[qrow][kb*16 + 4g + j],
    // scale*log2e folded in at cast time.
    const int    qrow = qt * 64 + wave * 16 + qi;
    const float* Qrow = Qg + base + (size_t)qrow * D;
    f16x4 qf[4];
#pragma unroll
    for (int kb = 0; kb < 4; ++kb) {
        float4 x = *reinterpret_cast<const float4*>(Qrow + kb * 16 + 4 * g);
        qf[kb] = f16x4{(f16)(x.x * SL2E), (f16)(x.y * SL2E),
                       (f16)(x.z * SL2E), (f16)(x.w * SL2E)};
    }

    float m_run = -INFINITY;
    float l_run = 0.f;
    f32x4 acc[4] = {};  // acc[dt][r] = out^T[d = dt*16 + 4g + r][q = qi]

    for (int kv0 = 0; kv0 < N; kv0 += 64) {
        __syncthreads();  // previous iteration's LDS reads done
        // Stage K (row-major f16) and V (transposed f16): 1024 float4s each,
        // 4 per thread, fully coalesced global reads.
#pragma unroll
        for (int i = 0; i < 4; ++i) {
            int idx = tid + 256 * i;     // float4 index in 64x64 tile
            int row = idx >> 4, c4 = idx & 15;
            float4 a = K4[(size_t)(kv0 + row) * 16 + c4];
            *reinterpret_cast<f16x4*>(&Kl[row][c4 * 4]) =
                f16x4{(f16)a.x, (f16)a.y, (f16)a.z, (f16)a.w};
            float4 v = V4[(size_t)(kv0 + row) * 16 + c4];
            Vt[c4 * 4 + 0][row] = (f16)v.x;
            Vt[c4 * 4 + 1][row] = (f16)v.y;
            Vt[c4 * 4 + 2][row] = (f16)v.z;
            Vt[c4 * 4 + 3][row] = (f16)v.w;
        }
        __syncthreads();

        // S^T = K_tile @ Q^T : st[t][r] = S^T[kv = t*16 + 4g + r][q = qi]
        f32x4 st[4];
#pragma unroll
        for (int t = 0; t < 4; ++t) {
            f32x4 a = {0.f, 0.f, 0.f, 0.f};
#pragma unroll
            for (int kb = 0; kb < 4; ++kb) {
                f16x4 kf = *reinterpret_cast<const f16x4*>(&Kl[t * 16 + qi][kb * 16 + 4 * g]);
                a = __builtin_amdgcn_mfma_f32_16x16x16f16(kf, qf[kb], a, 0, 0, 0);
            }
            st[t] = a;
        }

        // Online softmax (log2 domain; all 16 values in-lane belong to q=qi).
        float mt = -INFINITY;
#pragma unroll
        for (int t = 0; t < 4; ++t)
#pragma unroll
            for (int r = 0; r < 4; ++r) mt = fmaxf(mt, st[t][r]);
        mt = fmaxf(mt, __shfl_xor(mt, 16));
        mt = fmaxf(mt, __shfl_xor(mt, 32));
        const float mnew = fmaxf(m_run, mt);
        const float corr = __builtin_amdgcn_exp2f(m_run - mnew);

        float ps = 0.f;
        f16x4 pf[4];  // P^T fragments: reg j == B-operand k index. Free!
#pragma unroll
        for (int t = 0; t < 4; ++t)
#pragma unroll
            for (int r = 0; r < 4; ++r) {
                float p = __builtin_amdgcn_exp2f(st[t][r] - mnew);
                ps += p;
                pf[t][r] = (f16)p;
            }
        ps += __shfl_xor(ps, 16);
        ps += __shfl_xor(ps, 32);
        l_run = l_run * corr + ps;
        m_run = mnew;
#pragma unroll
        for (int dt = 0; dt < 4; ++dt)
#pragma unroll
            for (int r = 0; r < 4; ++r) acc[dt][r] *= corr;

        // out^T += V^T @ P^T
#pragma unroll
        for (int dt = 0; dt < 4; ++dt)
#pragma unroll
            for (int t = 0; t < 4; ++t) {
                f16x4 vf = *reinterpret_cast<const f16x4*>(&Vt[dt * 16 + qi][t * 16 + 4 * g]);
                acc[dt] = __builtin_amdgcn_mfma_f32_16x16x16f16(vf, pf[t], acc[dt], 0, 0, 0);
            }
    }

    // Epilogue: normalize, transpose via LDS, coalesced float4 stores into
    // out[b][n][h*64 + d] where bh = b*16 + h.
    const float inv_l = 1.f / l_run;
    __syncthreads();  // everyone done reading K/V LDS before reuse
    float (*ot)[68] = reinterpret_cast<float(*)[68]>(smem + (size_t)wave * 16 * 68 * sizeof(float));
#pragma unroll
    for (int dt = 0; dt < 4; ++dt)
#pragma unroll
        for (int r = 0; r < 4; ++r)
            ot[qi][dt * 16 + 4 * g + r] = acc[dt][r] * inv_l;
    __syncthreads();

    const int b = bh >> 4, h = bh & 15;
#pragma unroll
    for (int i = 0; i < 4; ++i) {
        int row = i * 4 + g;                 // row within wave's 16-row tile
        int n   = qt * 64 + wave * 16 + row;
        float4 val = *reinterpret_cast<const float4*>(&ot[row][4 * qi]);
        float4* dst = reinterpret_cast<float4*>(Og + ((size_t)b * N + n) * 1024 + h * 64) + qi;
        *dst = val;
    }
}

extern "C" void kernel_launch(void* const* d_in, const int* in_sizes, int n_in,
                              void* d_out, int out_size, void* d_ws, size_t ws_size,
                              hipStream_t stream) {
    const float* Q = (const float*)d_in[0];
    const float* K = (const float*)d_in[1];
    const float* V = (const float*)d_in[2];
    float* O = (float*)d_out;
    fattn<<<dim3(32 * 32), dim3(256), 0, stream>>>(Q, K, V, O);
}

// Round 3
// 164.763 us; speedup vs baseline: 1.2634x; 1.2634x over previous
//
#include <hip/hip_runtime.h>

// AttentionBase: B=32 (2 batch x 16 heads), N=2048, D=64, fp32 in/out.
// Flash-attention fwd, fp16 MFMA, fp32 accum.
// Round 3: T14 async-stage + double-buffered LDS (1 barrier/iter),
// K=32 MFMA for QK^T, conflict-free K strides, XCD swizzle, setprio.

using f16 = _Float16;
typedef __attribute__((ext_vector_type(4))) f16   f16x4;
typedef __attribute__((ext_vector_type(8))) f16   f16x8;
typedef __attribute__((ext_vector_type(4))) float f32x4;

constexpr int   N    = 2048;
constexpr float SL2E = 0.125f * 1.4426950408889634f;  // SCALE*log2(e), folded into Q
constexpr int   KSTR = 72;  // K tile LDS row stride (f16): 36 dw == 4 mod 32 -> conflict-free b128 reads + f16x4 writes
constexpr int   VSTR = 68;  // V^T LDS row stride (f16): 8B-aligned rows for b64 reads

__global__ __launch_bounds__(256, 4) void fattn(const float* __restrict__ Qg,
                                                const float* __restrict__ Kg,
                                                const float* __restrict__ Vg,
                                                float* __restrict__ Og)
{
    // Double-buffered K [2][64][KSTR] + V^T [2][64][VSTR], f16. 35840 B.
    // Epilogue reuses bytes 0..17407 as 4x float[16][68].
    __shared__ alignas(16) char smem[(2 * 64 * KSTR + 2 * 64 * VSTR) * 2];

    const int tid  = threadIdx.x;
    const int wave = tid >> 6;
    const int lane = tid & 63;
    const int g    = lane >> 4;   // 4-lane-group (0..3)
    const int qi   = lane & 15;   // q index within wave tile

    // XCD-aware swizzle: blockIdx%8 == XCD; give each XCD 4 contiguous bh
    // (4 MB K/V working set -> fits per-XCD L2). 1024 % 8 == 0 -> bijective.
    const int swz = (blockIdx.x & 7) * 128 + (blockIdx.x >> 3);
    const int bh = swz >> 5;   // batch-head 0..31
    const int qt = swz & 31;   // q tile 0..31

    const size_t base = (size_t)bh * N * 64;
    const float4* K4 = reinterpret_cast<const float4*>(Kg + base);
    const float4* V4 = reinterpret_cast<const float4*>(Vg + base);

    // Q fragments for 16x16x32 MFMA B-operand: lane holds Q[qrow][kb*32+8g+j], j=0..7.
    const int    qrow = qt * 64 + wave * 16 + qi;
    const float* Qrow = Qg + base + (size_t)qrow * 64;
    f16x8 qf[2];
#pragma unroll
    for (int kb = 0; kb < 2; ++kb) {
        float4 x0 = *reinterpret_cast<const float4*>(Qrow + kb * 32 + 8 * g);
        float4 x1 = *reinterpret_cast<const float4*>(Qrow + kb * 32 + 8 * g + 4);
        qf[kb] = f16x8{(f16)(x0.x * SL2E), (f16)(x0.y * SL2E), (f16)(x0.z * SL2E), (f16)(x0.w * SL2E),
                       (f16)(x1.x * SL2E), (f16)(x1.y * SL2E), (f16)(x1.z * SL2E), (f16)(x1.w * SL2E)};
    }

    float m_run = -INFINITY;
    float l_run = 0.f;
    f32x4 acc[4] = {};  // acc[dt][r] = out^T[d=dt*16+4g+r][q=qi]

    // Register staging for next KV tile (T14: issue early, write late).
    float4 kr[4], vr[4];
    auto LOAD = [&](int kv0) {
#pragma unroll
        for (int i = 0; i < 4; ++i) {
            int idx = tid + 256 * i, row = idx >> 4, c4 = idx & 15;
            kr[i] = K4[(size_t)(kv0 + row) * 16 + c4];
            vr[i] = V4[(size_t)(kv0 + row) * 16 + c4];
        }
    };
    auto STORE = [&](int b) {
        f16 (*kl)[KSTR] = reinterpret_cast<f16(*)[KSTR]>(smem + b * 64 * KSTR * 2);
        f16 (*vt)[VSTR] = reinterpret_cast<f16(*)[VSTR]>(smem + (2 * 64 * KSTR + b * 64 * VSTR) * 2);
#pragma unroll
        for (int i = 0; i < 4; ++i) {
            int idx = tid + 256 * i, row = idx >> 4, c4 = idx & 15;
            float4 a = kr[i];
            *reinterpret_cast<f16x4*>(&kl[row][c4 * 4]) =
                f16x4{(f16)a.x, (f16)a.y, (f16)a.z, (f16)a.w};
            float4 v = vr[i];
            vt[c4 * 4 + 0][row] = (f16)v.x;
            vt[c4 * 4 + 1][row] = (f16)v.y;
            vt[c4 * 4 + 2][row] = (f16)v.z;
            vt[c4 * 4 + 3][row] = (f16)v.w;
        }
    };

    LOAD(0);
    STORE(0);
    __syncthreads();

    for (int t = 0; t < 32; ++t) {
        const int cur = t & 1;
        if (t < 31) LOAD((t + 1) * 64);  // overlaps with compute below

        f16 (*kl)[KSTR] = reinterpret_cast<f16(*)[KSTR]>(smem + cur * 64 * KSTR * 2);
        f16 (*vt)[VSTR] = reinterpret_cast<f16(*)[VSTR]>(smem + (2 * 64 * KSTR + cur * 64 * VSTR) * 2);

        // S^T = K_tile @ Q^T via 16x16x32: st[t2][r] = S^T[kv=16t2+4g+r][q=qi]
        f32x4 st[4];
        __builtin_amdgcn_s_setprio(1);
#pragma unroll
        for (int t2 = 0; t2 < 4; ++t2) {
            f32x4 a = {0.f, 0.f, 0.f, 0.f};
#pragma unroll
            for (int kb = 0; kb < 2; ++kb) {
                f16x8 kf = *reinterpret_cast<const f16x8*>(&kl[t2 * 16 + qi][kb * 32 + 8 * g]);
                a = __builtin_amdgcn_mfma_f32_16x16x32_f16(kf, qf[kb], a, 0, 0, 0);
            }
            st[t2] = a;
        }
        __builtin_amdgcn_s_setprio(0);

        // Online softmax (log2 domain), lane-local + 2 shfls.
        float mt = -INFINITY;
#pragma unroll
        for (int t2 = 0; t2 < 4; ++t2)
#pragma unroll
            for (int r = 0; r < 4; ++r) mt = fmaxf(mt, st[t2][r]);
        mt = fmaxf(mt, __shfl_xor(mt, 16));
        mt = fmaxf(mt, __shfl_xor(mt, 32));
        const float mnew = fmaxf(m_run, mt);
        const float corr = __builtin_amdgcn_exp2f(m_run - mnew);

        float ps = 0.f;
        f16x4 pf[4];  // P^T fragments: reg j == PV B-operand k index (free).
#pragma unroll
        for (int t2 = 0; t2 < 4; ++t2)
#pragma unroll
            for (int r = 0; r < 4; ++r) {
                float p = __builtin_amdgcn_exp2f(st[t2][r] - mnew);
                ps += p;
                pf[t2][r] = (f16)p;
            }
        ps += __shfl_xor(ps, 16);
        ps += __shfl_xor(ps, 32);
        l_run = l_run * corr + ps;
        m_run = mnew;
#pragma unroll
        for (int dt = 0; dt < 4; ++dt)
#pragma unroll
            for (int r = 0; r < 4; ++r) acc[dt][r] *= corr;

        // out^T += V^T @ P^T (16x16x16)
        __builtin_amdgcn_s_setprio(1);
#pragma unroll
        for (int dt = 0; dt < 4; ++dt)
#pragma unroll
            for (int t2 = 0; t2 < 4; ++t2) {
                f16x4 vf = *reinterpret_cast<const f16x4*>(&vt[dt * 16 + qi][t2 * 16 + 4 * g]);
                acc[dt] = __builtin_amdgcn_mfma_f32_16x16x16f16(vf, pf[t2], acc[dt], 0, 0, 0);
            }
        __builtin_amdgcn_s_setprio(0);

        if (t < 31) {
            STORE(cur ^ 1);     // vmcnt wait lands here, hidden under compute
            __syncthreads();    // single barrier per iter (dbuf makes it safe)
        }
    }

    // Epilogue: normalize, transpose via LDS, coalesced float4 stores into
    // out[b][n][h*64+d], bh = b*16 + h.
    const float inv_l = 1.f / l_run;
    __syncthreads();  // all waves done with K/V LDS before reuse
    float (*ot)[68] = reinterpret_cast<float(*)[68]>(smem + (size_t)wave * 16 * 68 * sizeof(float));
#pragma unroll
    for (int dt = 0; dt < 4; ++dt)
#pragma unroll
        for (int r = 0; r < 4; ++r)
            ot[qi][dt * 16 + 4 * g + r] = acc[dt][r] * inv_l;
    // wave-local region: no cross-wave barrier needed before reading back

    const int b = bh >> 4, h = bh & 15;
#pragma unroll
    for (int i = 0; i < 4; ++i) {
        int row = i * 4 + g;
        int n   = qt * 64 + wave * 16 + row;
        float4 val = *reinterpret_cast<const float4*>(&ot[row][4 * qi]);
        float4* dst = reinterpret_cast<float4*>(Og + ((size_t)b * N + n) * 1024 + h * 64) + qi;
        *dst = val;
    }
}

extern "C" void kernel_launch(void* const* d_in, const int* in_sizes, int n_in,
                              void* d_out, int out_size, void* d_ws, size_t ws_size,
                              hipStream_t stream) {
    const float* Q = (const float*)d_in[0];
    const float* K = (const float*)d_in[1];
    const float* V = (const float*)d_in[2];
    float* O = (float*)d_out;
    fattn<<<dim3(32 * 32), dim3(256), 0, stream>>>(Q, K, V, O);
}

// Round 5
// 159.522 us; speedup vs baseline: 1.3049x; 1.0328x over previous
//
#include <hip/hip_runtime.h>

// AttentionBase: B=32 (2 batch x 16 heads), N=2048, D=64, fp32 in/out.
// Flash-attention fwd, fp16 MFMA, fp32 accum.
// Round 5 = round 4 with the cvt_pkrtz type binding fixed (bit_cast wrapper):
// XOR-swizzled K/V LDS (conflict-free staging writes + reads), register 4x4
// V transpose with vector LDS writes, packed cvt (pkrtz), defer-rescale (T13).
// Keeps: T14 dbuf 1-barrier loop, XCD swizzle, setprio.

using f16 = _Float16;
typedef __attribute__((ext_vector_type(2))) f16   f16x2;
typedef __attribute__((ext_vector_type(4))) f16   f16x4;
typedef __attribute__((ext_vector_type(8))) f16   f16x8;
typedef __attribute__((ext_vector_type(4))) float f32x4;

// __builtin_amdgcn_cvt_pkrtz returns an __fp16-based vector; bit_cast to our
// _Float16-based f16x2 (identical layout).
static __device__ __forceinline__ f16x2 pk(float a, float b) {
    return __builtin_bit_cast(f16x2, __builtin_amdgcn_cvt_pkrtz(a, b));
}

constexpr int   N    = 2048;
constexpr float SL2E = 0.125f * 1.4426950408889634f;  // SCALE*log2(e), folded into Q

// LDS layout (dbuf): K[2][64][64] f16 XOR-swizzled at 16B-chunk granularity
// (chunk c'=c^(row&7)); V^T[2][64][64] f16 swizzled at 8B-chunk granularity
// (chunk c'=c^((d^(d>>2))&15)). Both: staging writes AND fragment reads are
// bank-conflict-free. Total 32 KiB -> 4 blk/CU.

__global__ __launch_bounds__(256, 4) void fattn(const float* __restrict__ Qg,
                                                const float* __restrict__ Kg,
                                                const float* __restrict__ Vg,
                                                float* __restrict__ Og)
{
    __shared__ alignas(16) char smem[32768];

    const int tid  = threadIdx.x;
    const int wave = tid >> 6;
    const int lane = tid & 63;
    const int g    = lane >> 4;   // 4-lane-group (0..3)
    const int qi   = lane & 15;   // q index within wave tile

    // XCD-aware swizzle: each XCD gets 4 contiguous bh (4 MB K/V -> its L2).
    const int swz = (blockIdx.x & 7) * 128 + (blockIdx.x >> 3);
    const int bh = swz >> 5;
    const int qt = swz & 31;

    const size_t base = (size_t)bh * N * 64;
    const f32x4* K4 = reinterpret_cast<const f32x4*>(Kg + base);
    const f32x4* V4 = reinterpret_cast<const f32x4*>(Vg + base);

    // Q fragments (16x16x32 B-operand): lane holds Q[qrow][kb*32+8g+j], j=0..7.
    const int    qrow = qt * 64 + wave * 16 + qi;
    const float* Qrow = Qg + base + (size_t)qrow * 64;
    f16x8 qf[2];
#pragma unroll
    for (int kb = 0; kb < 2; ++kb) {
        f32x4 x0 = *reinterpret_cast<const f32x4*>(Qrow + kb * 32 + 8 * g);
        f32x4 x1 = *reinterpret_cast<const f32x4*>(Qrow + kb * 32 + 8 * g + 4);
        qf[kb] = f16x8{(f16)(x0[0] * SL2E), (f16)(x0[1] * SL2E), (f16)(x0[2] * SL2E), (f16)(x0[3] * SL2E),
                       (f16)(x1[0] * SL2E), (f16)(x1[1] * SL2E), (f16)(x1[2] * SL2E), (f16)(x1[3] * SL2E)};
    }

    // Per-thread constant staging indices.
    const int voff  = 64 * (tid >> 4) + (tid & 15);  // V load: f32x4 idx
    const int vrow4 = tid >> 4;                      // kv/4 group transposed
    const int vc4   = tid & 15;                      // d/4 group transposed

    // Per-thread constant V^T read swizzles (per dt).
    int vswz[4], vrow[4];
#pragma unroll
    for (int dt = 0; dt < 4; ++dt) {
        int d = dt * 16 + qi;
        vswz[dt] = (d ^ (d >> 2)) & 15;
        vrow[dt] = d * 128;  // byte row base
    }

    float m_run = -INFINITY;
    float l_run = 0.f;
    f32x4 acc[4] = {};  // acc[dt][r] = out^T[d=dt*16+4g+r][q=qi]

    f32x4 kr[4], vr[4];
    auto LOAD = [&](int kv0) {
#pragma unroll
        for (int i = 0; i < 4; ++i) kr[i] = K4[kv0 * 16 + tid + 256 * i];
#pragma unroll
        for (int j = 0; j < 4; ++j) vr[j] = V4[kv0 * 16 + voff + 16 * j];
    };
    auto STORE = [&](int b) {
        char* kb_ = smem + b * 8192;
        char* vb_ = smem + 16384 + b * 8192;
        // K: row-major, 16B-chunk XOR swizzle c' = c ^ (row&7).
#pragma unroll
        for (int i = 0; i < 4; ++i) {
            int idx = tid + 256 * i, row = idx >> 4, c4 = idx & 15;
            f16x2 lo = pk(kr[i][0], kr[i][1]);
            f16x2 hi = pk(kr[i][2], kr[i][3]);
            f16x4 w  = __builtin_shufflevector(lo, hi, 0, 1, 2, 3);
            int off = row * 128 + (((c4 >> 1) ^ (row & 7)) << 4) + ((c4 & 1) << 3);
            *reinterpret_cast<f16x4*>(kb_ + off) = w;
        }
        // V^T: register 4x4 transpose, 8B-chunk XOR swizzle.
#pragma unroll
        for (int jj = 0; jj < 4; ++jj) {
            int d = vc4 * 4 + jj;
            f16x2 lo = pk(vr[0][jj], vr[1][jj]);
            f16x2 hi = pk(vr[2][jj], vr[3][jj]);
            f16x4 w  = __builtin_shufflevector(lo, hi, 0, 1, 2, 3);
            int off = d * 128 + ((vrow4 ^ ((d ^ (d >> 2)) & 15)) << 3);
            *reinterpret_cast<f16x4*>(vb_ + off) = w;
        }
    };

    LOAD(0);
    STORE(0);
    __syncthreads();

    for (int t = 0; t < 32; ++t) {
        const int cur = t & 1;
        if (t < 31) LOAD((t + 1) * 64);  // global latency hides under compute

        const char* kb_ = smem + cur * 8192;
        const char* vb_ = smem + 16384 + cur * 8192;

        // S^T = K_tile @ Q^T (16x16x32): st[t2][r] = S^T[kv=16t2+4g+r][q=qi]
        f32x4 st[4];
        __builtin_amdgcn_s_setprio(1);
#pragma unroll
        for (int t2 = 0; t2 < 4; ++t2) {
            f32x4 a = {0.f, 0.f, 0.f, 0.f};
            int row = t2 * 16 + qi;
#pragma unroll
            for (int kb = 0; kb < 2; ++kb) {
                int c16 = (4 * kb + g) ^ (row & 7);
                f16x8 kk = *reinterpret_cast<const f16x8*>(kb_ + row * 128 + c16 * 16);
                a = __builtin_amdgcn_mfma_f32_16x16x32_f16(kk, qf[kb], a, 0, 0, 0);
            }
            st[t2] = a;
        }
        __builtin_amdgcn_s_setprio(0);

        // Online softmax (log2 domain), lane-local + 2 shfls.
        float mt = -INFINITY;
#pragma unroll
        for (int t2 = 0; t2 < 4; ++t2)
#pragma unroll
            for (int r = 0; r < 4; ++r) mt = fmaxf(mt, st[t2][r]);
        mt = fmaxf(mt, __shfl_xor(mt, 16));
        mt = fmaxf(mt, __shfl_xor(mt, 32));

        // T13 defer-rescale: skip acc rescale when no lane's max grew.
        if (!__all(mt <= m_run)) {
            const float mnew = fmaxf(m_run, mt);
            const float corr = __builtin_amdgcn_exp2f(m_run - mnew);
            l_run *= corr;
#pragma unroll
            for (int dt = 0; dt < 4; ++dt)
#pragma unroll
                for (int r = 0; r < 4; ++r) acc[dt][r] *= corr;
            m_run = mnew;
        }

        float ps = 0.f;
        f16x4 pf[4];  // P^T fragments: reg j == PV B-operand k index.
#pragma unroll
        for (int t2 = 0; t2 < 4; ++t2) {
            float p0 = __builtin_amdgcn_exp2f(st[t2][0] - m_run);
            float p1 = __builtin_amdgcn_exp2f(st[t2][1] - m_run);
            float p2 = __builtin_amdgcn_exp2f(st[t2][2] - m_run);
            float p3 = __builtin_amdgcn_exp2f(st[t2][3] - m_run);
            ps += (p0 + p1) + (p2 + p3);
            f16x2 lo = pk(p0, p1);
            f16x2 hi = pk(p2, p3);
            pf[t2] = __builtin_shufflevector(lo, hi, 0, 1, 2, 3);
        }
        ps += __shfl_xor(ps, 16);
        ps += __shfl_xor(ps, 32);
        l_run += ps;

        // out^T += V^T @ P^T (16x16x16)
        __builtin_amdgcn_s_setprio(1);
#pragma unroll
        for (int dt = 0; dt < 4; ++dt)
#pragma unroll
            for (int t2 = 0; t2 < 4; ++t2) {
                int c = (t2 * 4 + g) ^ vswz[dt];
                f16x4 vf = *reinterpret_cast<const f16x4*>(vb_ + vrow[dt] + c * 8);
                acc[dt] = __builtin_amdgcn_mfma_f32_16x16x16f16(vf, pf[t2], acc[dt], 0, 0, 0);
            }
        __builtin_amdgcn_s_setprio(0);

        if (t < 31) {
            STORE(cur ^ 1);   // vmcnt drain + LDS write, hidden after compute
            __syncthreads();  // single barrier per iter (dbuf makes it safe)
        }
    }

    // Epilogue: normalize, transpose via LDS, coalesced f32x4 stores into
    // out[b][n][h*64+d], bh = b*16 + h.
    const float inv_l = 1.f / l_run;
    __syncthreads();  // all waves done with K/V LDS before reuse
    float (*ot)[68] = reinterpret_cast<float(*)[68]>(smem + (size_t)wave * 16 * 68 * sizeof(float));
#pragma unroll
    for (int dt = 0; dt < 4; ++dt)
#pragma unroll
        for (int r = 0; r < 4; ++r)
            ot[qi][dt * 16 + 4 * g + r] = acc[dt][r] * inv_l;
    // wave-local region; in-wave LDS RAW handled by lgkmcnt.

    const int b = bh >> 4, h = bh & 15;
#pragma unroll
    for (int i = 0; i < 4; ++i) {
        int row = i * 4 + g;
        int n   = qt * 64 + wave * 16 + row;
        f32x4 val = *reinterpret_cast<const f32x4*>(&ot[row][4 * qi]);
        f32x4* dst = reinterpret_cast<f32x4*>(Og + ((size_t)b * N + n) * 1024 + h * 64) + qi;
        *dst = val;
    }
}

extern "C" void kernel_launch(void* const* d_in, const int* in_sizes, int n_in,
                              void* d_out, int out_size, void* d_ws, size_t ws_size,
                              hipStream_t stream) {
    const float* Q = (const float*)d_in[0];
    const float* K = (const float*)d_in[1];
    const float* V = (const float*)d_in[2];
    float* O = (float*)d_out;
    fattn<<<dim3(32 * 32), dim3(256), 0, stream>>>(Q, K, V, O);
}